// Round 15
// baseline (90.601 us; speedup 1.0000x reference)
//
#include <hip/hip_runtime.h>
#include <hip/hip_fp16.h>
#include <hip/hip_cooperative_groups.h>
#include <cstddef>

namespace cg = cooperative_groups;

#define BATCH 64
#define HW 512
#define RVAL (1.0f / 512.0f)   // r = c = 1/512, exact in fp32
#define EPS_ 1e-6f
#define MAXIT 100
#define NBLK 256               // == CU count: cooperative launch always fits
#define NTHR 1024              // 16 waves/block
#define SPIN_BOUND 4000000     // convert any sync failure into absmax, not hang

__device__ __forceinline__ unsigned h2u(__half2 h) {
    union { __half2 h; unsigned u; } c; c.h = h; return c.u;
}
__device__ __forceinline__ __half2 u2h(unsigned u) {
    union { unsigned u; __half2 h; } c; c.u = u; return c.h;
}

// R9 skeleton (43 us proven: part[16] fp32 one-step reduce, tid0 counting
// barrier, relaxed agent atomics, no fences in loop) + ONE delta:
// sweep 0 also writes K = exp(-M) as fp16 into a BLOCK-PRIVATE 32 MB global
// scratch slab; iteration sweeps and the final pass stream Kh instead of M:
// half the bytes per sweep (128 KB/CU -> ~L2-resident) and zero exp.
// Kh is written and read only by its owning block -> ordinary loads/stores,
// no visibility machinery. fp16-K numerics validated in R10 (absmax 2.98e-8).
// mode==0 falls back to exact R9 behavior when ws_size is too small.
// Lane blocking: lane l owns cols [8l, 8l+8) (16B-contiguous in Kh).
__global__ __launch_bounds__(NTHR, 4)
void sinkhorn_kh(const float* __restrict__ M, float* __restrict__ P,
                 __half* __restrict__ Kh, float* __restrict__ colpart,
                 int* __restrict__ bar, int mode, int tail_mode) {
    const int tid  = threadIdx.x;
    const int bid  = blockIdx.x;
    const int b    = bid >> 2;     // batch (4 blocks per batch)
    const int slab = bid & 3;      // 128-row slab
    const int w    = tid >> 6;     // wave 0..15 (owns rows w*8..w*8+8)
    const int l    = tid & 63;     // lane: cols [8l, 8l+8)

    cg::grid_group grid = cg::this_grid();

    __shared__ float part[16][HW];   // 32 KB, one-step reduce (R9)
    __shared__ float v_lds[HW];      // 2 KB

    if (tid < HW) v_lds[tid] = 1.0f;
    __syncthreads();

    const size_t row0 = (size_t)b * HW + (size_t)slab * 128;
    const float4* Mb  = (const float4*)(M + row0 * HW);
    __half*       Khb = Kh + row0 * HW;      // block-private slab

    float u_loc[8];
    for (int it = 0; it < MAXIT; ++it) {
        float4 v0 = *(const float4*)&v_lds[l * 8];
        float4 v1 = *(const float4*)&v_lds[l * 8 + 4];
        float4 cp0 = make_float4(0.f, 0.f, 0.f, 0.f);
        float4 cp1 = make_float4(0.f, 0.f, 0.f, 0.f);

        if (it == 0) {
            // ---- sweep 0: M from global, exp, (mode1: pack Kh), marginals --
#pragma unroll
            for (int rr = 0; rr < 8; ++rr) {
                const int row = w * 8 + rr;
                const float4* mp = Mb + (size_t)row * 128;
                float4 m0 = mp[2 * l];
                float4 m1 = mp[2 * l + 1];
                float4 k0, k1;
                k0.x = __expf(-m0.x); k0.y = __expf(-m0.y);
                k0.z = __expf(-m0.z); k0.w = __expf(-m0.w);
                k1.x = __expf(-m1.x); k1.y = __expf(-m1.y);
                k1.z = __expf(-m1.z); k1.w = __expf(-m1.w);
                if (mode) {
                    uint4 q;
                    q.x = h2u(__floats2half2_rn(k0.x, k0.y));
                    q.y = h2u(__floats2half2_rn(k0.z, k0.w));
                    q.z = h2u(__floats2half2_rn(k1.x, k1.y));
                    q.w = h2u(__floats2half2_rn(k1.z, k1.w));
                    *(uint4*)&Khb[(size_t)row * HW + 8 * l] = q;
                }
                float s = k0.x * v0.x + k0.y * v0.y + k0.z * v0.z + k0.w * v0.w
                        + k1.x * v1.x + k1.y * v1.y + k1.z * v1.z + k1.w * v1.w;
#pragma unroll
                for (int off = 32; off >= 1; off >>= 1)
                    s += __shfl_xor(s, off, 64);
                float u = RVAL / s;
                u_loc[rr] = u;
                cp0.x += u * k0.x; cp0.y += u * k0.y;
                cp0.z += u * k0.z; cp0.w += u * k0.w;
                cp1.x += u * k1.x; cp1.y += u * k1.y;
                cp1.z += u * k1.z; cp1.w += u * k1.w;
            }
        } else if (mode) {
            // ---- iteration sweep: Kh fp16 stream, no exp ----
#pragma unroll
            for (int rr = 0; rr < 8; ++rr) {
                const int row = w * 8 + rr;
                uint4 q = *(const uint4*)&Khb[(size_t)row * HW + 8 * l];
                float2 a0 = __half22float2(u2h(q.x));
                float2 a1 = __half22float2(u2h(q.y));
                float2 b0 = __half22float2(u2h(q.z));
                float2 b1 = __half22float2(u2h(q.w));
                float s = a0.x * v0.x + a0.y * v0.y + a1.x * v0.z + a1.y * v0.w
                        + b0.x * v1.x + b0.y * v1.y + b1.x * v1.z + b1.y * v1.w;
#pragma unroll
                for (int off = 32; off >= 1; off >>= 1)
                    s += __shfl_xor(s, off, 64);
                float u = RVAL / s;
                u_loc[rr] = u;
                cp0.x += u * a0.x; cp0.y += u * a0.y;
                cp0.z += u * a1.x; cp0.w += u * a1.y;
                cp1.x += u * b0.x; cp1.y += u * b0.y;
                cp1.z += u * b1.x; cp1.w += u * b1.y;
            }
        } else {
            // ---- mode-0 fallback: R9 iteration sweep (M + exp) ----
#pragma unroll
            for (int rr = 0; rr < 8; ++rr) {
                const int row = w * 8 + rr;
                const float4* mp = Mb + (size_t)row * 128;
                float4 m0 = mp[2 * l];
                float4 m1 = mp[2 * l + 1];
                float4 k0, k1;
                k0.x = __expf(-m0.x); k0.y = __expf(-m0.y);
                k0.z = __expf(-m0.z); k0.w = __expf(-m0.w);
                k1.x = __expf(-m1.x); k1.y = __expf(-m1.y);
                k1.z = __expf(-m1.z); k1.w = __expf(-m1.w);
                float s = k0.x * v0.x + k0.y * v0.y + k0.z * v0.z + k0.w * v0.w
                        + k1.x * v1.x + k1.y * v1.y + k1.z * v1.z + k1.w * v1.w;
#pragma unroll
                for (int off = 32; off >= 1; off >>= 1)
                    s += __shfl_xor(s, off, 64);
                float u = RVAL / s;
                u_loc[rr] = u;
                cp0.x += u * k0.x; cp0.y += u * k0.y;
                cp0.z += u * k0.z; cp0.w += u * k0.w;
                cp1.x += u * k1.x; cp1.y += u * k1.y;
                cp1.z += u * k1.z; cp1.w += u * k1.w;
            }
        }

        // ---- R9-verbatim exchange (8-col/lane part indexing) ----
        *(float4*)&part[w][l * 8]     = cp0;
        *(float4*)&part[w][l * 8 + 4] = cp1;
        __syncthreads();

        float* slot = colpart + ((size_t)((it & 1) * NBLK + bid)) * HW;
        if (tid < HW) {
            float t = 0.f;
#pragma unroll
            for (int ww = 0; ww < 16; ++ww) t += part[ww][tid];
            __hip_atomic_store(&slot[tid], t, __ATOMIC_RELAXED,
                               __HIP_MEMORY_SCOPE_AGENT);
        }
        __syncthreads();   // drains vmcnt: stores at L3 before flag bump

        int* bs = bar + b * MAXIT + it;
        if (tid == 0) {
            __hip_atomic_fetch_add(bs, 1, __ATOMIC_RELAXED,
                                   __HIP_MEMORY_SCOPE_AGENT);
            int guard = 0;
            while (__hip_atomic_load(bs, __ATOMIC_RELAXED,
                                     __HIP_MEMORY_SCOPE_AGENT) < 4 &&
                   guard < SPIN_BOUND) {
                __builtin_amdgcn_s_sleep(4);
                ++guard;
            }
        }
        __syncthreads();

        float tt = 0.f;
        int viol = 0;
        if (tid < HW) {
            const float* basep =
                colpart + ((size_t)((it & 1) * NBLK + b * 4)) * HW;
#pragma unroll
            for (int bb = 0; bb < 4; ++bb)
                tt += __hip_atomic_load(basep + bb * HW + tid, __ATOMIC_RELAXED,
                                        __HIP_MEMORY_SCOPE_AGENT);
            viol = fabsf(v_lds[tid] * tt - RVAL) > EPS_;
        }
        int any = __syncthreads_or(viol);   // identical on all 4 blocks
        if (!any) break;            // converged: keep u_loc and current v
        if (tid < HW) v_lds[tid] = RVAL / tt;
        __syncthreads();
    }

    // Only when colpart aliases d_out's tail: rendezvous before P stores.
    if (tail_mode) grid.sync();

    // ---- final: P = diag(u) K diag(v) ----
    float4 fv0 = *(const float4*)&v_lds[l * 8];
    float4 fv1 = *(const float4*)&v_lds[l * 8 + 4];
    float4* Pb = (float4*)(P + row0 * HW);
#pragma unroll
    for (int rr = 0; rr < 8; ++rr) {
        const int row = w * 8 + rr;
        float u = u_loc[rr];
        float4 o0, o1;
        if (mode) {
            uint4 q = *(const uint4*)&Khb[(size_t)row * HW + 8 * l];
            float2 a0 = __half22float2(u2h(q.x));
            float2 a1 = __half22float2(u2h(q.y));
            float2 b0 = __half22float2(u2h(q.z));
            float2 b1 = __half22float2(u2h(q.w));
            o0.x = u * a0.x * fv0.x; o0.y = u * a0.y * fv0.y;
            o0.z = u * a1.x * fv0.z; o0.w = u * a1.y * fv0.w;
            o1.x = u * b0.x * fv1.x; o1.y = u * b0.y * fv1.y;
            o1.z = u * b1.x * fv1.z; o1.w = u * b1.y * fv1.w;
        } else {
            const float4* mp = Mb + (size_t)row * 128;
            float4 m0 = mp[2 * l];
            float4 m1 = mp[2 * l + 1];
            o0.x = u * __expf(-m0.x) * fv0.x; o0.y = u * __expf(-m0.y) * fv0.y;
            o0.z = u * __expf(-m0.z) * fv0.z; o0.w = u * __expf(-m0.w) * fv0.w;
            o1.x = u * __expf(-m1.x) * fv1.x; o1.y = u * __expf(-m1.y) * fv1.y;
            o1.z = u * __expf(-m1.z) * fv1.z; o1.w = u * __expf(-m1.w) * fv1.w;
        }
        Pb[(size_t)row * 128 + 2 * l]     = o0;
        Pb[(size_t)row * 128 + 2 * l + 1] = o1;
    }
}

extern "C" void kernel_launch(void* const* d_in, const int* in_sizes, int n_in,
                              void* d_out, int out_size, void* d_ws, size_t ws_size,
                              hipStream_t stream) {
    const float* M = (const float*)d_in[0];
    float* P = (float*)d_out;

    const size_t KH_BYTES  = (size_t)BATCH * HW * HW * sizeof(__half);  // 32 MB
    const size_t CP_BYTES  = (size_t)2 * NBLK * HW * sizeof(float);     // 1 MB
    const size_t BAR_BYTES = (size_t)BATCH * MAXIT * sizeof(int);       // 25.6 KB

    __half* Kh;
    float*  colpart;
    int*    bar;
    int mode, tail_mode;

    if (ws_size >= KH_BYTES + CP_BYTES + BAR_BYTES) {
        mode = 1; tail_mode = 0;
        Kh      = (__half*)d_ws;
        colpart = (float*)((char*)d_ws + KH_BYTES);
        bar     = (int*)((char*)d_ws + KH_BYTES + CP_BYTES);
    } else if (ws_size >= CP_BYTES + BAR_BYTES) {
        mode = 0; tail_mode = 0;
        Kh      = (__half*)d_ws;     // unused in mode 0
        colpart = (float*)d_ws;
        bar     = (int*)((char*)d_ws + CP_BYTES);
    } else {
        mode = 0; tail_mode = 1;     // colpart in d_out tail; P gated by sync
        char* scratch = (char*)d_out + (size_t)out_size * sizeof(float)
                        - (CP_BYTES + BAR_BYTES);
        Kh      = (__half*)scratch;  // unused in mode 0
        colpart = (float*)scratch;
        bar     = (int*)(scratch + CP_BYTES);
    }

    hipMemsetAsync(bar, 0, BAR_BYTES, stream);

    void* args[] = { (void*)&M, (void*)&P, (void*)&Kh, (void*)&colpart,
                     (void*)&bar, (void*)&mode, (void*)&tail_mode };
    hipLaunchCooperativeKernel((const void*)sinkhorn_kh, dim3(NBLK),
                               dim3(NTHR), args, 0, stream);
}

// Round 16
// 68.180 us; speedup vs baseline: 1.3288x; 1.3288x over previous
//
#include <hip/hip_runtime.h>
#include <hip/hip_cooperative_groups.h>
#include <cstddef>

namespace cg = cooperative_groups;

#define BATCH 64
#define HW 512
#define RVAL (1.0f / 512.0f)   // r = c = 1/512, exact in fp32
#define EPS_ 1e-6f
#define MAXIT 100
#define NBLK 256               // == CU count: cooperative launch always fits
#define NTHR 1024              // 16 waves/block
#define SPIN_BOUND 4000000     // convert any sync failure into absmax, not hang

typedef float f32x4 __attribute__((ext_vector_type(4)));

// Round-9 kernel, byte-for-byte (43 us dispatch, proven optimum across
// R10/R12/R14/R15 which all regressed), plus two zero-risk deltas:
//  (a) bounded tid0 spin (R13 lesson: hang -> absmax, not timeout);
//  (b) nontemporal final P stores (P never re-read; skip L2 allocation).
// Structure: 4 blocks/batch sweep 128-row slabs on all 256 CUs; fused
// row-sum + column-partial sweep; cross-block exchange via relaxed
// agent-scope atomics only (coherent-point L3, no fences -> per-XCD L2
// stays resident); per-batch tid0 counting barrier; 5 block barriers/iter.
__global__ __launch_bounds__(NTHR, 4)
void sinkhorn_atm2(const float* __restrict__ M, float* __restrict__ P,
                   float* __restrict__ colpart, int* __restrict__ bar,
                   int tail_mode) {
    const int tid  = threadIdx.x;
    const int bid  = blockIdx.x;
    const int b    = bid >> 2;     // batch (4 blocks per batch)
    const int slab = bid & 3;      // 128-row slab
    const int w    = tid >> 6;     // wave 0..15 (owns 8 rows)
    const int l    = tid & 63;     // lane: cols [4l,4l+4) and [256+4l,..)

    cg::grid_group grid = cg::this_grid();

    __shared__ float v_lds[HW];
    __shared__ float part[16][HW];   // per-wave column partials (32 KB)

    if (tid < HW) v_lds[tid] = 1.0f;
    __syncthreads();

    const float4* Mb = (const float4*)(M + ((size_t)b * HW + slab * 128) * HW);

    float u_loc[8];
    for (int it = 0; it < MAXIT; ++it) {
        // ---- fused sweep over this block's 128-row slab (L3-resident) ----
        float4 v0 = *(const float4*)&v_lds[l * 4];
        float4 v1 = *(const float4*)&v_lds[256 + l * 4];
        float4 cp0 = make_float4(0.f, 0.f, 0.f, 0.f);
        float4 cp1 = make_float4(0.f, 0.f, 0.f, 0.f);
#pragma unroll
        for (int rr = 0; rr < 8; ++rr) {
            const float4* mp = Mb + (size_t)(w * 8 + rr) * 128;
            float4 m0 = mp[l];
            float4 m1 = mp[64 + l];
            float4 k0, k1;
            k0.x = __expf(-m0.x); k0.y = __expf(-m0.y);
            k0.z = __expf(-m0.z); k0.w = __expf(-m0.w);
            k1.x = __expf(-m1.x); k1.y = __expf(-m1.y);
            k1.z = __expf(-m1.z); k1.w = __expf(-m1.w);
            float s = k0.x * v0.x + k0.y * v0.y + k0.z * v0.z + k0.w * v0.w
                    + k1.x * v1.x + k1.y * v1.y + k1.z * v1.z + k1.w * v1.w;
#pragma unroll
            for (int off = 32; off >= 1; off >>= 1)
                s += __shfl_xor(s, off, 64);
            float u = RVAL / s;            // replicated across wave
            u_loc[rr] = u;
            cp0.x += u * k0.x; cp0.y += u * k0.y;
            cp0.z += u * k0.z; cp0.w += u * k0.w;
            cp1.x += u * k1.x; cp1.y += u * k1.y;
            cp1.z += u * k1.z; cp1.w += u * k1.w;
        }
        *(float4*)&part[w][l * 4]       = cp0;
        *(float4*)&part[w][256 + l * 4] = cp1;
        __syncthreads();

        // ---- publish this block's 512 column sums (coherent-point stores) --
        float* slot = colpart + ((size_t)((it & 1) * NBLK + bid)) * HW;
        if (tid < HW) {
            float t = 0.f;
#pragma unroll
            for (int ww = 0; ww < 16; ++ww) t += part[ww][tid];
            __hip_atomic_store(&slot[tid], t, __ATOMIC_RELAXED,
                               __HIP_MEMORY_SCOPE_AGENT);
        }
        __syncthreads();   // drains vmcnt: stores are at L3 before flag bump

        // ---- per-batch counting barrier, relaxed atomics only ----
        int* bs = bar + b * MAXIT + it;
        if (tid == 0) {
            __hip_atomic_fetch_add(bs, 1, __ATOMIC_RELAXED,
                                   __HIP_MEMORY_SCOPE_AGENT);
            int guard = 0;
            while (__hip_atomic_load(bs, __ATOMIC_RELAXED,
                                     __HIP_MEMORY_SCOPE_AGENT) < 4 &&
                   guard < SPIN_BOUND) {
                __builtin_amdgcn_s_sleep(4);
                ++guard;
            }
        }
        __syncthreads();

        // ---- combine 4 slabs (fixed order: deterministic); convergence ----
        float tt = 0.f;
        int viol = 0;
        if (tid < HW) {
            const float* basep =
                colpart + ((size_t)((it & 1) * NBLK + b * 4)) * HW;
#pragma unroll
            for (int bb = 0; bb < 4; ++bb)
                tt += __hip_atomic_load(basep + bb * HW + tid, __ATOMIC_RELAXED,
                                        __HIP_MEMORY_SCOPE_AGENT);
            viol = fabsf(v_lds[tid] * tt - RVAL) > EPS_;
        }
        int any = __syncthreads_or(viol);   // identical on all 4 blocks
        if (!any) break;            // converged: keep u_loc and current v
        if (tid < HW) v_lds[tid] = RVAL / tt;
        __syncthreads();
    }

    // Only when scratch aliases d_out's tail: rendezvous before P stores.
    if (tail_mode) grid.sync();

    // ---- final: P = diag(u) K diag(v); nontemporal stores (P not re-read) --
    float4 fv0 = *(const float4*)&v_lds[l * 4];
    float4 fv1 = *(const float4*)&v_lds[256 + l * 4];
    f32x4* Pb = (f32x4*)(P + ((size_t)b * HW + slab * 128) * HW);
#pragma unroll
    for (int rr = 0; rr < 8; ++rr) {
        float u = u_loc[rr];
        const float4* mp = Mb + (size_t)(w * 8 + rr) * 128;
        float4 m0 = mp[l];
        float4 m1 = mp[64 + l];
        f32x4 o0, o1;
        o0.x = u * __expf(-m0.x) * fv0.x; o0.y = u * __expf(-m0.y) * fv0.y;
        o0.z = u * __expf(-m0.z) * fv0.z; o0.w = u * __expf(-m0.w) * fv0.w;
        o1.x = u * __expf(-m1.x) * fv1.x; o1.y = u * __expf(-m1.y) * fv1.y;
        o1.z = u * __expf(-m1.z) * fv1.z; o1.w = u * __expf(-m1.w) * fv1.w;
        __builtin_nontemporal_store(o0, Pb + (size_t)(w * 8 + rr) * 128 + l);
        __builtin_nontemporal_store(o1, Pb + (size_t)(w * 8 + rr) * 128 + 64 + l);
    }
}

extern "C" void kernel_launch(void* const* d_in, const int* in_sizes, int n_in,
                              void* d_out, int out_size, void* d_ws, size_t ws_size,
                              hipStream_t stream) {
    const float* M = (const float*)d_in[0];
    float* P = (float*)d_out;

    const size_t CP_BYTES  = (size_t)2 * NBLK * HW * sizeof(float);  // 1 MB
    const size_t BAR_BYTES = (size_t)BATCH * MAXIT * sizeof(int);    // 25.6 KB
    const size_t NEED = CP_BYTES + BAR_BYTES;

    char* scratch;
    int tail_mode;
    if (ws_size >= NEED) {
        scratch = (char*)d_ws;
        tail_mode = 0;
    } else {
        // tail of d_out; P stores are gated by the post-loop grid.sync
        scratch = (char*)d_out + (size_t)out_size * sizeof(float) - NEED;
        tail_mode = 1;
    }
    float* colpart = (float*)scratch;
    int*   bar     = (int*)(scratch + CP_BYTES);

    hipMemsetAsync(bar, 0, BAR_BYTES, stream);

    void* args[] = { (void*)&M, (void*)&P, (void*)&colpart, (void*)&bar,
                     (void*)&tail_mode };
    hipLaunchCooperativeKernel((const void*)sinkhorn_atm2, dim3(NBLK),
                               dim3(NTHR), args, 0, stream);
}